// Round 3
// baseline (227.152 us; speedup 1.0000x reference)
//
#include <hip/hip_runtime.h>

// PSAMask collect: out[n, i*65+j, h, w] = x[n, (i-h+64)*129 + (j-w+64), h, w]
// Pure gather (mask window fully covers offsets). Tile = (n,i,h): stage 129-row
// trapezoid via async global_load_lds, skewed LDS reads, coalesced row stores.
// R3: persistent blocks, double-buffered LDS pipeline -> loads stay in flight
// across the whole store phase (MLP fix).

constexpr int H = 65, W = 65, MH = 129, MW = 129, HALF = 64;
constexpr int HW = H * W;            // 4225
constexpr int PITCH = 66;            // skew-read lane delta -65 == -1 mod 32: conflict-free
constexpr int TILE_F = MH * PITCH;   // 8514 floats per buffer
constexpr int NTILES = 4 * H * H;    // 16900
constexpr int GRID = 1024;           // %8==0 -> simple bijective XCD swizzle

__global__ __launch_bounds__(512, 4)
void psamask_collect(const float* __restrict__ x, float* __restrict__ out) {
    extern __shared__ float lds[];   // 2 * 8514 * 4 = 68112 B -> 2 blocks/CU

    // XCD swizzle: chunk l on xcd (blockIdx%8); consecutive tiles in a chunk are
    // h-adjacent -> adjacent 260B output segments merge in the same XCD's L2.
    int l = (blockIdx.x & 7) * (GRID / 8) + (blockIdx.x >> 3);
    constexpr int q = NTILES / GRID;     // 16
    constexpr int r = NTILES % GRID;     // 516
    int start = l * q + (l < r ? l : r);
    int cnt   = q + (l < r ? 1 : 0);

    int wave = threadIdx.x >> 6;
    int lane = threadIdx.x & 63;

    // Async trapezoid staging: row u used for w in [max(0,64-u), min(65,129-u)).
    // All loads issue with no waitcnt; the next __syncthreads drains them.
    auto stage = [&](float* buf, int t) {
        int n   = t / (H * H);
        int rem = t - n * (H * H);
        int i   = rem / H;
        int h   = rem - i * H;
        int Mh  = i - h + HALF;          // in [0,128]
        const float* src = x + (size_t)(n * (MH * MW) + Mh * MW) * HW + h * W;
        for (int u = wave; u < MH; u += 8) {
            int lo = HALF - u; if (lo < 0) lo = 0;
            int hi = MH - u;   if (hi > W) hi = W;
            const float* rowp = src + (size_t)u * HW;
            for (int w0 = lo; w0 < hi; w0 += 64) {
                int w = w0 + lane;
                if (w < hi) {
                    __builtin_amdgcn_global_load_lds(
                        (const __attribute__((address_space(1))) unsigned int*)(rowp + w),
                        (__attribute__((address_space(3))) unsigned int*)(&buf[u * PITCH + w0]),
                        4, 0, 0);
                }
            }
        }
    };

    stage(lds, start);                       // prologue prefetch into buf0
    for (int k = 0; k < cnt; ++k) {
        float* bufc = lds + (k & 1) * TILE_F;
        float* bufn = lds + ((k & 1) ^ 1) * TILE_F;
        __syncthreads();                     // vmcnt(0) drain: bufc staged; barrier: prev reads done
        if (k + 1 < cnt) stage(bufn, start + k + 1);   // prefetch next tile (hides under store)

        int t   = start + k;
        int n   = t / (H * H);
        int rem = t - n * (H * H);
        int i   = rem / H;
        int h   = rem - i * H;
        float* dst = out + (size_t)n * HW * HW + (size_t)(i * W) * HW + h * W;
        for (int f = threadIdx.x; f < W * W; f += 512) {
            int j = f / W;
            int w = f - j * W;
            dst[(size_t)j * HW + w] = bufc[(j - w + HALF) * PITCH + w];
        }
    }
}

extern "C" void kernel_launch(void* const* d_in, const int* in_sizes, int n_in,
                              void* d_out, int out_size, void* d_ws, size_t ws_size,
                              hipStream_t stream) {
    const float* x = (const float*)d_in[0];
    float* out = (float*)d_out;
    (void)in_sizes; (void)n_in; (void)out_size; (void)d_ws; (void)ws_size;
    psamask_collect<<<dim3(GRID), dim3(512), 2 * TILE_F * sizeof(float), stream>>>(x, out);
}

// Round 4
// 164.373 us; speedup vs baseline: 1.3819x; 1.3819x over previous
//
#include <hip/hip_runtime.h>

// PSAMask collect: out[n, i*65+j, h, w] = x[n, (i-h+64)*129 + (j-w+64), h, w]
// Pure gather. Block per (n,i,h). R4: R2 envelope (34KB LDS, 4 blocks/CU,
// 32 waves/CU) + sliding-window j-chunk pipeline with counted vmcnt:
// chunk j in [16k,16k+16) needs rows u in [16k, 16k+80). Prologue stages 80
// rows; each phase issues next 16 rows (2 loads/wave, deterministic) BEFORE
// its 2 uniform stores, then waits vmcnt(2): needed loads (older) drained,
// this phase's stores + nothing else left outstanding -> reads stay in
// flight across store phases, no full drains mid-tile.

constexpr int H = 65, W = 65, MH = 129, MW = 129, HALF = 64;
constexpr int HW = H * W;          // 4225
constexpr int PITCH = 66;          // skew-read lane delta -65: conflict-free
constexpr int NWG = 4 * H * H;     // 16900

__device__ __forceinline__ void ldsld(const float* g, float* l) {
    __builtin_amdgcn_global_load_lds(
        (const __attribute__((address_space(1))) unsigned int*)g,
        (__attribute__((address_space(3))) unsigned int*)l, 4, 0, 0);
}

__global__ __launch_bounds__(512, 4)
void psamask_collect(const float* __restrict__ x, float* __restrict__ out) {
    __shared__ float lds[MH * PITCH];  // 34,056 B

    // Bijective XCD-aware swizzle (16900 % 8 == 4 -> m204 formula)
    constexpr int NX = 8, q = NWG / NX, r = NWG % NX;
    int b = blockIdx.x;
    int xcd = b % NX, idx = b / NX;
    int logical = (xcd < r ? xcd * (q + 1) : r * (q + 1) + (xcd - r) * q) + idx;

    int n   = logical / (H * H);
    int rem = logical - n * (H * H);
    int i   = rem / H;
    int h   = rem - i * H;
    int Mh  = i - h + HALF;            // in [0,128]

    const float* src = x + (size_t)(n * (MH * MW) + Mh * MW) * HW + h * W;
    float* dst = out + (size_t)n * HW * HW + (size_t)(i * W) * HW + (size_t)h * W;
    int wave = threadIdx.x >> 6;
    int lane = threadIdx.x & 63;

    // Single-instruction row stage for u >= 65 (lo = 0, len = 129-u <= 64)
    auto stage1 = [&](int u) {
        int hi = MH - u;
        if (lane < hi) ldsld(src + (size_t)u * HW + lane, &lds[u * PITCH]);
    };

    // Uniform store of chunk elements [0,1024): exactly 2 stores per wave.
    auto store1024 = [&](int j0) {
        #pragma unroll
        for (int s = 0; s < 2; ++s) {
            int f  = (int)threadIdx.x + s * 512;   // < 1024: always valid
            int jj = f / W;
            int w  = f - jj * W;
            int j  = j0 + jj;
            dst[(size_t)j * HW + w] = lds[(j - w + HALF) * PITCH + w];
        }
    };

    // Prologue: rows [0,80) (trapezoid rows, 1-2 insts each)
    for (int r2 = 0; r2 < 10; ++r2) {
        int u = wave + 8 * r2;                 // covers 0..79
        int lo = HALF - u; if (lo < 0) lo = 0;
        int hi = MH - u;   if (hi > W) hi = W;
        const float* rowp = src + (size_t)u * HW;
        for (int w0 = lo; w0 < hi; w0 += 64) {
            int w = w0 + lane;
            if (w < hi) ldsld(rowp + w, &lds[u * PITCH + w0]);
        }
    }
    asm volatile("s_waitcnt vmcnt(0)" ::: "memory");
    __builtin_amdgcn_s_barrier();

    // Phase 0: issue rows [80,96), store chunk0 (j 0..15, elems 0..1023)
    stage1(80 + 2 * wave); stage1(81 + 2 * wave);
    store1024(0);
    asm volatile("s_waitcnt vmcnt(2)" ::: "memory");   // rows [80,96) done; my 2 stores may remain
    __builtin_amdgcn_s_barrier();

    // Phase 1: issue rows [96,112), store chunk1
    stage1(96 + 2 * wave); stage1(97 + 2 * wave);
    store1024(16);
    asm volatile("s_waitcnt vmcnt(2)" ::: "memory");
    __builtin_amdgcn_s_barrier();

    // Phase 2: issue rows [112,129), store chunk2
    stage1(112 + 2 * wave); stage1(113 + 2 * wave);
    if (wave == 7) stage1(128);                 // extra load is older than stores -> drained below
    store1024(32);
    asm volatile("s_waitcnt vmcnt(2)" ::: "memory");
    __builtin_amdgcn_s_barrier();

    // Phase 3: chunk3 (j 48..64, 1105 elems) + the 16-elem tails of chunks 0-2
    {
        constexpr int MAIN = 17 * W;            // 1105
        for (int f = (int)threadIdx.x; f < MAIN + 48; f += 512) {
            int j, w;
            if (f < MAIN) {
                int jj = f / W; w = f - jj * W; j = 48 + jj;
            } else {
                int e = f - MAIN;               // 0..47
                int c = e >> 4;                 // chunk 0..2
                w = 49 + (e & 15);
                j = 16 * c + 15;
            }
            dst[(size_t)j * HW + w] = lds[(j - w + HALF) * PITCH + w];
        }
    }
}

extern "C" void kernel_launch(void* const* d_in, const int* in_sizes, int n_in,
                              void* d_out, int out_size, void* d_ws, size_t ws_size,
                              hipStream_t stream) {
    const float* x = (const float*)d_in[0];
    float* out = (float*)d_out;
    (void)in_sizes; (void)n_in; (void)out_size; (void)d_ws; (void)ws_size;
    psamask_collect<<<dim3(NWG), dim3(512), 0, stream>>>(x, out);
}